// Round 18
// baseline (462.203 us; speedup 1.0000x reference)
//
#include <hip/hip_runtime.h>

typedef unsigned short u16;
typedef unsigned int u32;
typedef __bf16 bf16x8 __attribute__((ext_vector_type(8)));
typedef float f32x4 __attribute__((ext_vector_type(4)));

#define MFMA_BF16(a, b, c) __builtin_amdgcn_mfma_f32_16x16x32_bf16(a, b, c, 0, 0, 0)

#define NBUC_MAX 512
#define BCAP 4608
#define EPB 2048  // edges per bucket-scatter block

__device__ __forceinline__ float bf2f(u16 h) {
  u32 u = ((u32)h) << 16;
  return __builtin_bit_cast(float, u);
}
__device__ __forceinline__ u16 f2bf_sw(float f) {
  u32 u = __builtin_bit_cast(u32, f);
  u += 0x7fffu + ((u >> 16) & 1u);
  return (u16)(u >> 16);
}
// packed f32x2 -> bf16x2. HW cvt: WIN in epilogues (r14). Loop-body pk-math asm:
// LOSS twice (r10, r14). fdot2_bf16: WRONG for per-feature sums (r17 — it merges
// the feature pair into one scalar). Neither goes back in.
#if __has_builtin(__builtin_amdgcn_cvt_pk_bf16_f32)
__device__ __forceinline__ u32 f2bf_pk(float a, float b) {
  auto r = __builtin_amdgcn_cvt_pk_bf16_f32(a, b);
  return __builtin_bit_cast(u32, r);
}
#else
__device__ __forceinline__ u32 f2bf_pk(float a, float b) {
  return (u32)f2bf_sw(a) | ((u32)f2bf_sw(b) << 16);
}
#endif
__device__ __forceinline__ u16 f2bf(float f) { return (u16)f2bf_pk(f, f); }

// ---- fused setup: [0,384) weight prep | [384,384+V) mlp0 table | rest: bucket scatter.
__global__ __launch_bounds__(256) void setup_all(
    const float* __restrict__ w0, const float* __restrict__ w1c, const float* __restrict__ w2c,
    const float* __restrict__ w3, const float* __restrict__ w4, const float* __restrict__ w5,
    u16* __restrict__ wt, const float* __restrict__ emb, const float* __restrict__ iw1,
    const float* __restrict__ ib1, const float* __restrict__ iw2, const float* __restrict__ ib2,
    u16* __restrict__ table, int V_, const int* __restrict__ src, const int* __restrict__ dst,
    u32* __restrict__ pairs, u32* __restrict__ cursor, int E_, int nbuc) {
  __shared__ u32 smem[1024];  // bucket: lcnt|lbase ; mlp0: e|tt (aliased)
  const int t = threadIdx.x;
  int bid = blockIdx.x;
  if (bid < 384) {  // ---- weight prep
    const int which = bid >> 6;
    const float* w = which == 0 ? w0 : which == 1 ? w1c : which == 2 ? w2c
                    : which == 3 ? w3 : which == 4 ? w4 : w5;
    int tt_ = (bid & 63) * 256 + t;
    int n = tt_ >> 7, k = tt_ & 127;
    wt[which * 16384 + n * 128 + k] = f2bf(w[k * 128 + n]);
    return;
  }
  bid -= 384;
  if (bid < V_) {  // ---- initial MLP on the 500-row embedding table
    float* e = (float*)smem;
    float* tb = e + 128;
    if (t < 128) e[t] = emb[bid * 128 + t];
    __syncthreads();
    if (t < 128) {
      float s = ib1[t];
      for (int k = 0; k < 128; ++k) s += e[k] * iw1[k * 128 + t];
      tb[t] = s > 0.f ? s : 0.f;
    }
    __syncthreads();
    if (t < 128) {
      float s2 = ib2[t];
      for (int k = 0; k < 128; ++k) s2 += tb[k] * iw2[k * 128 + t];
      table[bid * 128 + t] = f2bf(s2);
    }
    return;
  }
  bid -= V_;
  {  // ---- bucket edges by dst>>8, packed (src<<8)|dloc, int4 edge reads
    u32* lcnt = smem;
    u32* lbase = smem + 512;
    for (int b = t; b < NBUC_MAX; b += 256) lcnt[b] = 0;
    __syncthreads();
    const int e0 = bid * EPB;
#pragma unroll
    for (int it = 0; it < EPB / 1024; ++it) {
      int e = e0 + it * 1024 + t * 4;
      if (e + 3 < E_) {
        int4 d4 = *(const int4*)(dst + e);
        atomicAdd(&lcnt[((u32)d4.x) >> 8], 1u);
        atomicAdd(&lcnt[((u32)d4.y) >> 8], 1u);
        atomicAdd(&lcnt[((u32)d4.z) >> 8], 1u);
        atomicAdd(&lcnt[((u32)d4.w) >> 8], 1u);
      } else {
        for (int k = 0; k < 4; ++k)
          if (e + k < E_) atomicAdd(&lcnt[((u32)dst[e + k]) >> 8], 1u);
      }
    }
    __syncthreads();
    for (int b = t; b < nbuc; b += 256) {
      u32 c = lcnt[b];
      lbase[b] = c ? atomicAdd(&cursor[b], c) : 0u;
      lcnt[b] = 0;
    }
    __syncthreads();
#define PUTPAIR(dd, ss)                                            \
  {                                                                \
    u32 b_ = ((u32)(dd)) >> 8;                                     \
    u32 r_ = atomicAdd(&lcnt[b_], 1u);                             \
    u32 p_ = lbase[b_] + r_;                                       \
    if (p_ < BCAP)                                                 \
      pairs[(size_t)b_ * BCAP + p_] = (((u32)(ss)) << 8) | (u32)((dd) & 255); \
  }
#pragma unroll
    for (int it = 0; it < EPB / 1024; ++it) {
      int e = e0 + it * 1024 + t * 4;
      if (e + 3 < E_) {
        int4 d4 = *(const int4*)(dst + e);
        int4 s4 = *(const int4*)(src + e);
        PUTPAIR(d4.x, s4.x)
        PUTPAIR(d4.y, s4.y)
        PUTPAIR(d4.z, s4.z)
        PUTPAIR(d4.w, s4.w)
      } else {
        for (int k = 0; k < 4; ++k)
          if (e + k < E_) PUTPAIR(dst[e + k], src[e + k])
      }
    }
#undef PUTPAIR
  }
}

// ---- per-bucket exact CSR (256 nodes/bucket): LDS count + scan + rank scatter
__global__ __launch_bounds__(256) void csr_build(const u32* __restrict__ pairs,
                                                 const u32* __restrict__ cursor,
                                                 u32* __restrict__ csr, int* __restrict__ RS,
                                                 int* __restrict__ DEG, int nrows) {
  __shared__ u32 cnt[256];
  __shared__ u32 offs[256];
  __shared__ u32 basearr[256];
  const int b = blockIdx.x, t = threadIdx.x;
  u32 count = cursor[b];
  if (count > BCAP) count = BCAP;
  cnt[t] = 0;
  __syncthreads();
  const u32* pb = pairs + (size_t)b * BCAP;
  for (u32 i = t * 4; i < count; i += 1024) {
    if (i + 3 < count) {
      uint4 v4 = *(const uint4*)(pb + i);
      atomicAdd(&cnt[v4.x & 255u], 1u);
      atomicAdd(&cnt[v4.y & 255u], 1u);
      atomicAdd(&cnt[v4.z & 255u], 1u);
      atomicAdd(&cnt[v4.w & 255u], 1u);
    } else {
      for (u32 k = 0; k < 4 && i + k < count; ++k) atomicAdd(&cnt[pb[i + k] & 255u], 1u);
    }
  }
  __syncthreads();
  const u32 my = cnt[t];
  offs[t] = my;
  __syncthreads();
  for (int d = 1; d < 256; d <<= 1) {
    u32 v = (t >= d) ? offs[t - d] : 0u;
    __syncthreads();
    offs[t] += v;
    __syncthreads();
  }
  const u32 excl = offs[t] - my;  // exclusive prefix
  const int node = (b << 8) + t;
  if (node < nrows) {
    RS[node] = b * BCAP + (int)excl;
    DEG[node] = (int)my;
  }
  basearr[t] = excl;
  cnt[t] = 0;
  __syncthreads();
#define SCAT(vv)                                          \
  {                                                       \
    u32 dl_ = (vv) & 255u;                                \
    u32 r_ = atomicAdd(&cnt[dl_], 1u);                    \
    csr[(size_t)b * BCAP + basearr[dl_] + r_] = (vv) >> 8; \
  }
  for (u32 i = t * 4; i < count; i += 1024) {
    if (i + 3 < count) {
      uint4 v4 = *(const uint4*)(pb + i);
      SCAT(v4.x)
      SCAT(v4.y)
      SCAT(v4.z)
      SCAT(v4.w)
    } else {
      for (u32 k = 0; k < 4 && i + k < count; ++k) SCAT(pb[i + k])
    }
  }
#undef SCAT
}

// ---- aggregation.
// MODE 0: AGG[i] = TBL[x[i]] + Σ TBL[x[j]] — r15-proven cvt+add ACCUM (fdot2 is
//   WRONG here: it merges the feature pair — r17).
// MODE 1 (factored BN, r17 bug fixed): relu(sc·x+sh) = sc·max(x,th) + sh, sc>0
//   (g=ones). Per node: AGG = sc·Σmax(x,th) + (deg+1)·sh. Inner loop 3 insts/elem
//   (was 4); the (deg+1)·sh correction applied once per node in the epilogue.
// Structure frozen (scalar math; 2-deep pipeline; 32-bit byte offsets).
template <int MODE>
__global__ __launch_bounds__(256) void agg_kernel(
    const u16* __restrict__ Hsrc, const int* __restrict__ x, const u32* __restrict__ csr,
    const int* __restrict__ RS, const int* __restrict__ DEG, const float* __restrict__ scsh,
    u16* __restrict__ AGG, int nrows) {
  int node = blockIdx.x * 4 + (threadIdx.x >> 6);
  if (node >= nrows) return;
  const int lane = threadIdx.x & 63;
  const int grp = lane >> 4;  // neighbor sub-slot 0..3
  const int fl = lane & 15;   // 16B feature chunk
  const int deg = DEG[node];
  const u32* cl = csr + RS[node];
  const char* Hb = (const char*)Hsrc;
  const u32 flo = (u32)fl << 4;

  float th[8];
  if (MODE == 1) {
#pragma unroll
    for (int i = 0; i < 8; ++i) th[i] = scsh[128 + fl * 8 + i];
  }
  float a[8];
#pragma unroll
  for (int i = 0; i < 8; ++i) a[i] = 0.f;

#define ACCUM(vv)                                   \
  {                                                 \
    const u16* p = (const u16*)&(vv);               \
    _Pragma("unroll") for (int i = 0; i < 8; ++i) { \
      float xv = bf2f(p[i]);                        \
      if (MODE == 1) xv = xv > th[i] ? xv : th[i];  \
      a[i] += xv;                                   \
    }                                               \
  }
#define ROWOFF(idx) ((((u32)(MODE == 0 ? x[(idx)] : (idx))) << 8) + flo)

  if (grp == 0) {
    uint4 v = *(const uint4*)(Hb + ROWOFF(node));
    ACCUM(v);
  }
  int j = grp;
  int cA = (j < deg) ? (int)cl[j] : 0;
  int cB = (j + 4 < deg) ? (int)cl[j + 4] : 0;
  uint4 nv = make_uint4(0u, 0u, 0u, 0u);
  if (j < deg) nv = *(const uint4*)(Hb + ROWOFF(cA));
  while (j < deg) {
    uint4 cv = nv;
    int cn = cB;
    cB = (j + 8 < deg) ? (int)cl[j + 8] : 0;
    if (j + 4 < deg) nv = *(const uint4*)(Hb + ROWOFF(cn));
    ACCUM(cv);
    j += 4;
  }
#undef ROWOFF
#undef ACCUM

#pragma unroll
  for (int i = 0; i < 8; ++i) {
    a[i] += __shfl_xor(a[i], 16);
    a[i] += __shfl_xor(a[i], 32);
  }
  if (grp == 0) {
    if (MODE == 1) {
      const float cnt = (float)(deg + 1);
#pragma unroll
      for (int i = 0; i < 8; ++i) {
        float sc = scsh[fl * 8 + i];
        float sh = scsh[256 + fl * 8 + i];
        a[i] = a[i] * sc + cnt * sh;  // the K·sh term r17 dropped
      }
    }
    u32 o[4];
#pragma unroll
    for (int i = 0; i < 4; ++i) o[i] = f2bf_pk(a[2 * i], a[2 * i + 1]);
    *(uint4*)(AGG + (size_t)node * 128 + fl * 8) = *(uint4*)o;
  }
}

// ---- fused 2-layer MLP (bf16 MFMA), 128x128 tile, 4 waves, T in-place, coalesced
// C-store via Xs (r13), HW cvt epilogues (r14), PART stats (r12). FROZEN.
__global__ __launch_bounds__(256) void mlp_kernel(
    const u16* __restrict__ X, const u16* __restrict__ W1t, const float* __restrict__ b1,
    const u16* __restrict__ W2t, const float* __restrict__ b2, u16* __restrict__ Y,
    float* __restrict__ part, int nrows) {
  __shared__ u16 Xs[128 * 136];
  const int t = threadIdx.x;
  const int row0 = blockIdx.x * 128;
  {
    const int seg = t & 15;
    const int rb = t >> 4;
#pragma unroll
    for (int p = 0; p < 8; ++p) {
      const int r = rb + p * 16;
      const int gr = row0 + r;
      uint4 v = make_uint4(0u, 0u, 0u, 0u);
      if (gr < nrows) v = *(const uint4*)(X + (size_t)gr * 128 + seg * 8);
      *(uint4*)(Xs + r * 136 + seg * 8) = v;
    }
  }
  __syncthreads();
  const int lane = t & 63;
  const int wave = t >> 6;
  const int n0 = wave * 32;
  const int nl = lane & 15;
  const int quad = lane >> 4;

  bf16x8 bw[2][4];
#pragma unroll
  for (int nt = 0; nt < 2; ++nt)
#pragma unroll
    for (int kk = 0; kk < 4; ++kk)
      bw[nt][kk] = *(const bf16x8*)(W1t + (size_t)(n0 + nt * 16 + nl) * 128 + kk * 32 + quad * 8);

  f32x4 acc[8][2];
#pragma unroll
  for (int mt = 0; mt < 8; ++mt) {
    acc[mt][0] = (f32x4)0.0f;
    acc[mt][1] = (f32x4)0.0f;
  }
#pragma unroll
  for (int kk = 0; kk < 4; ++kk) {
#pragma unroll
    for (int mt = 0; mt < 8; ++mt) {
      bf16x8 a = *(const bf16x8*)(Xs + (mt * 16 + nl) * 136 + kk * 32 + quad * 8);
      acc[mt][0] = MFMA_BF16(a, bw[0][kk], acc[mt][0]);
      acc[mt][1] = MFMA_BF16(a, bw[1][kk], acc[mt][1]);
    }
  }
  __syncthreads();  // all GEMM1 A-reads complete before overwriting Xs with T
#pragma unroll
  for (int nt = 0; nt < 2; ++nt) {
    const int n = n0 + nt * 16 + nl;
    const float bias = b1[n];
#pragma unroll
    for (int mt = 0; mt < 8; ++mt)
#pragma unroll
      for (int r = 0; r < 4; ++r) {
        float v = acc[mt][nt][r] + bias;
        v = v > 0.f ? v : 0.f;
        Xs[(mt * 16 + quad * 4 + r) * 136 + n] = f2bf(v);
      }
  }
  __syncthreads();
  // GEMM2
#pragma unroll
  for (int nt = 0; nt < 2; ++nt)
#pragma unroll
    for (int kk = 0; kk < 4; ++kk)
      bw[nt][kk] = *(const bf16x8*)(W2t + (size_t)(n0 + nt * 16 + nl) * 128 + kk * 32 + quad * 8);
#pragma unroll
  for (int mt = 0; mt < 8; ++mt) {
    acc[mt][0] = (f32x4)0.0f;
    acc[mt][1] = (f32x4)0.0f;
  }
#pragma unroll
  for (int kk = 0; kk < 4; ++kk) {
#pragma unroll
    for (int mt = 0; mt < 8; ++mt) {
      bf16x8 a = *(const bf16x8*)(Xs + (mt * 16 + nl) * 136 + kk * 32 + quad * 8);
      acc[mt][0] = MFMA_BF16(a, bw[0][kk], acc[mt][0]);
      acc[mt][1] = MFMA_BF16(a, bw[1][kk], acc[mt][1]);
    }
  }
  __syncthreads();  // all GEMM2 A-reads complete before overwriting Xs with C
  float ssum[2] = {0.f, 0.f}, ssq[2] = {0.f, 0.f};
#pragma unroll
  for (int nt = 0; nt < 2; ++nt) {
    const int n = n0 + nt * 16 + nl;
    const float bias = b2[n];
#pragma unroll
    for (int mt = 0; mt < 8; ++mt)
#pragma unroll
      for (int r = 0; r < 4; ++r) {
        const int row = row0 + mt * 16 + quad * 4 + r;
        float v = acc[mt][nt][r] + bias;
        if (row < nrows) {
          ssum[nt] += v;
          ssq[nt] += v * v;
        }
        Xs[(mt * 16 + quad * 4 + r) * 136 + n] = f2bf(v);
      }
  }
#pragma unroll
  for (int nt = 0; nt < 2; ++nt) {
    float s = ssum[nt], q = ssq[nt];
    s += __shfl_xor(s, 16);
    q += __shfl_xor(q, 16);
    s += __shfl_xor(s, 32);
    q += __shfl_xor(q, 32);
    if (quad == 0) {
      const int n = n0 + nt * 16 + nl;
      part[(size_t)blockIdx.x * 256 + n] = s;
      part[(size_t)blockIdx.x * 256 + 128 + n] = q;
    }
  }
  __syncthreads();
  {
    const int seg = t & 15;
    const int rb = t >> 4;
#pragma unroll
    for (int p = 0; p < 8; ++p) {
      const int r = rb + p * 16;
      const int gr = row0 + r;
      if (gr < nrows)
        *(uint4*)(Y + (size_t)gr * 128 + seg * 8) = *(const uint4*)(Xs + r * 136 + seg * 8);
    }
  }
}

// ---- parallel column-reduce of PART -> per-layer [sc | th | sh] (stride 384).
// th = mu - be/sc, sh = be - mu*sc. Valid since sc = rstd*g > 0 (g = ones).
__global__ __launch_bounds__(256) void bn_reduce_finalize(
    const float* __restrict__ part, int nblk, const float* __restrict__ g,
    const float* __restrict__ be, float invN, float* __restrict__ scsh) {
  __shared__ float red[2][128];
  const int c = blockIdx.x;  // 0..127
  const int t = threadIdx.x;
  const int half = t >> 7;
  const int tt = t & 127;
  const int col = c + half * 128;
  float s = 0.f;
  for (int b = tt; b < nblk; b += 128) s += part[(size_t)b * 256 + col];
  red[half][tt] = s;
  __syncthreads();
  for (int d = 64; d > 0; d >>= 1) {
    if (tt < d) red[half][tt] += red[half][tt + d];
    __syncthreads();
  }
  if (t == 0) {
    float mu = red[0][0] * invN;
    float var = red[1][0] * invN - mu * mu;
    float rstd = rsqrtf(var + 1e-5f);
    float sc = rstd * g[c];
    float sh = be[c] - mu * sc;
    scsh[c] = sc;
    scsh[128 + c] = mu - be[c] / sc;  // th
    scsh[256 + c] = sh;
  }
}

// ---- pooling (factored layer-3 BN: p = sc·Σmax(x,th) + count·sh) + final head
__global__ __launch_bounds__(256) void pool_final(
    const u16* __restrict__ Hh, const int* __restrict__ batch, const float* __restrict__ scsh,
    const float* __restrict__ f1w, const float* __restrict__ f1b, const float* __restrict__ f2w,
    const float* __restrict__ f2b, float* __restrict__ out, int nrows) {
  __shared__ float red[16][128];
  __shared__ float pr[128];
  __shared__ float tt[128];
  const int gid = blockIdx.x, t = threadIdx.x;
  int l = 0, r = nrows;
  while (l < r) {
    int m = (l + r) >> 1;
    if (batch[m] < gid) l = m + 1; else r = m;
  }
  const int s0 = l;
  r = nrows;
  while (l < r) {
    int m = (l + r) >> 1;
    if (batch[m] < gid + 1) l = m + 1; else r = m;
  }
  const int s1 = l;
  const int fl = t & 15;
  const int grp = t >> 4;
  float th[8];
#pragma unroll
  for (int i = 0; i < 8; ++i) th[i] = scsh[128 + fl * 8 + i];
  float a[8];
#pragma unroll
  for (int i = 0; i < 8; ++i) a[i] = 0.f;
  for (int i = s0 + grp; i < s1; i += 16) {
    uint4 v = *(const uint4*)(Hh + (size_t)i * 128 + fl * 8);
    const u16* pp = (const u16*)&v;
#pragma unroll
    for (int k = 0; k < 8; ++k) {
      float xv = bf2f(pp[k]);
      a[k] += xv > th[k] ? xv : th[k];
    }
  }
#pragma unroll
  for (int k = 0; k < 8; ++k) red[grp][fl * 8 + k] = a[k];
  __syncthreads();
  if (t < 128) {
    float s = 0.f;
#pragma unroll
    for (int gg2 = 0; gg2 < 16; ++gg2) s += red[gg2][t];
    pr[t] = s * scsh[t] + (float)(s1 - s0) * scsh[256 + t];  // sc·Σmax + count·sh
  }
  __syncthreads();
  if (t < 128) {
    float s = f1b[t];
    for (int k = 0; k < 128; ++k) s += pr[k] * f1w[k * 128 + t];
    tt[t] = s > 0.f ? s : 0.f;
  }
  __syncthreads();
  if (t < 10) {
    float s2 = f2b[t];
    for (int k = 0; k < 128; ++k) s2 += tt[k] * f2w[k * 10 + t];
    out[gid * 10 + t] = s2;
  }
}

// ws layout (bytes):
//   H     @ 0          : 25,600,000
//   AGG   @ 25,600,000 : 25,600,000
//   PAIRS @ 51,200,000 : 9,437,184
//   CSR   @ 60,637,184 : 9,437,184
//   RS    @ 70,074,368 : 400,000
//   DEG   @ 70,474,368 : 400,000
//   CUR   @ 70,874,368 : 2,048       (zeroed)
//   SCSH  @ 70,876,416 : 4,608       (3 layers x [sc|th|sh] = 384 f32)
//   WT    @ 70,881,024 : 196,608
//   TBL   @ 71,077,632 : 128,000
//   PART  @ 71,205,632 : 800,768
extern "C" void kernel_launch(void* const* d_in, const int* in_sizes, int n_in, void* d_out,
                              int out_size, void* d_ws, size_t ws_size, hipStream_t stream) {
  const int* x = (const int*)d_in[0];
  const int* ei = (const int*)d_in[1];
  const int* batch = (const int*)d_in[2];
  const float* emb = (const float*)d_in[3];
  const float* iw1 = (const float*)d_in[4];
  const float* ib1 = (const float*)d_in[5];
  const float* iw2 = (const float*)d_in[6];
  const float* ib2 = (const float*)d_in[7];
  const float* f1w = (const float*)d_in[8];
  const float* f1b = (const float*)d_in[9];
  const float* f2w = (const float*)d_in[10];
  const float* f2b = (const float*)d_in[11];
  const float* cw1[3] = {(const float*)d_in[12], (const float*)d_in[18], (const float*)d_in[24]};
  const float* cb1[3] = {(const float*)d_in[13], (const float*)d_in[19], (const float*)d_in[25]};
  const float* cw2[3] = {(const float*)d_in[14], (const float*)d_in[20], (const float*)d_in[26]};
  const float* cb2[3] = {(const float*)d_in[15], (const float*)d_in[21], (const float*)d_in[27]};
  const float* gg[3] = {(const float*)d_in[16], (const float*)d_in[22], (const float*)d_in[28]};
  const float* bb[3] = {(const float*)d_in[17], (const float*)d_in[23], (const float*)d_in[29]};

  const int N_ = in_sizes[0];
  const int E_ = in_sizes[1] / 2;
  const int V_ = in_sizes[3] / 128;
  const int G_ = out_size / 10;
  const int NBUC = (N_ + 255) >> 8;
  const int NBUCKBLK = (E_ + EPB - 1) / EPB;
  const float invN = 1.0f / (float)N_;

  char* ws = (char*)d_ws;
  u16* H = (u16*)(ws + 0);
  u16* AGG = (u16*)(ws + 25600000);
  u32* PAIRS = (u32*)(ws + 51200000);
  u32* CSR = (u32*)(ws + 60637184);
  int* RS = (int*)(ws + 70074368);
  int* DEG = (int*)(ws + 70474368);
  u32* CUR = (u32*)(ws + 70874368);
  float* SCSH = (float*)(ws + 70876416);
  u16* WT = (u16*)(ws + 70881024);
  u16* TBL = (u16*)(ws + 71077632);
  float* PART = (float*)(ws + 71205632);

  hipMemsetAsync(ws + 70874368, 0, 2048, stream);  // CUR only

  setup_all<<<384 + V_ + NBUCKBLK, 256, 0, stream>>>(
      cw1[0], cw2[0], cw1[1], cw2[1], cw1[2], cw2[2], WT, emb, iw1, ib1, iw2, ib2, TBL, V_,
      ei, ei + E_, PAIRS, CUR, E_, NBUC);
  csr_build<<<NBUC, 256, 0, stream>>>(PAIRS, CUR, CSR, RS, DEG, N_);

  const int ablk = (N_ + 3) / 4;
  const int mblk = (N_ + 127) / 128;
  for (int l = 0; l < 3; ++l) {
    const u16* W1 = WT + (size_t)l * 32768;
    const u16* W2 = WT + (size_t)l * 32768 + 16384;
    if (l == 0)
      agg_kernel<0><<<ablk, 256, 0, stream>>>(TBL, x, CSR, RS, DEG, nullptr, AGG, N_);
    else
      agg_kernel<1><<<ablk, 256, 0, stream>>>(H, nullptr, CSR, RS, DEG, SCSH + (l - 1) * 384,
                                              AGG, N_);
    mlp_kernel<<<mblk, 256, 0, stream>>>(AGG, W1, cb1[l], W2, cb2[l], H, PART, N_);
    bn_reduce_finalize<<<128, 256, 0, stream>>>(PART, mblk, gg[l], bb[l], invN,
                                                SCSH + l * 384);
  }
  pool_final<<<G_, 256, 0, stream>>>(H, batch, SCSH + 2 * 384, f1w, f1b, f2w, f2b,
                                     (float*)d_out, N_);
}

// Round 19
// 450.938 us; speedup vs baseline: 1.0250x; 1.0250x over previous
//
#include <hip/hip_runtime.h>

typedef unsigned short u16;
typedef unsigned int u32;
typedef __bf16 bf16x8 __attribute__((ext_vector_type(8)));
typedef float f32x4 __attribute__((ext_vector_type(4)));

#define MFMA_BF16(a, b, c) __builtin_amdgcn_mfma_f32_16x16x32_bf16(a, b, c, 0, 0, 0)

#define NBUC_MAX 512
#define BCAP 4608
#define EPB 2048  // edges per bucket-scatter block

__device__ __forceinline__ float bf2f(u16 h) {
  u32 u = ((u32)h) << 16;
  return __builtin_bit_cast(float, u);
}
__device__ __forceinline__ u16 f2bf_sw(float f) {
  u32 u = __builtin_bit_cast(u32, f);
  u += 0x7fffu + ((u >> 16) & 1u);
  return (u16)(u >> 16);
}
// packed f32x2 -> bf16x2. HW cvt: WIN in epilogues (r14). Inner-loop rewrites all
// REGRESSED: pk-math asm (r10 +4us, r14 +3.9us), factored-BN max-form (r18 +5us),
// fdot2 (r17: wrong semantics). The r13/r15 scalar fma form is the measured optimum.
#if __has_builtin(__builtin_amdgcn_cvt_pk_bf16_f32)
__device__ __forceinline__ u32 f2bf_pk(float a, float b) {
  auto r = __builtin_amdgcn_cvt_pk_bf16_f32(a, b);
  return __builtin_bit_cast(u32, r);
}
#else
__device__ __forceinline__ u32 f2bf_pk(float a, float b) {
  return (u32)f2bf_sw(a) | ((u32)f2bf_sw(b) << 16);
}
#endif
__device__ __forceinline__ u16 f2bf(float f) { return (u16)f2bf_pk(f, f); }

// ---- fused setup: [0,384) weight prep | [384,384+V) mlp0 table | rest: bucket scatter.
__global__ __launch_bounds__(256) void setup_all(
    const float* __restrict__ w0, const float* __restrict__ w1c, const float* __restrict__ w2c,
    const float* __restrict__ w3, const float* __restrict__ w4, const float* __restrict__ w5,
    u16* __restrict__ wt, const float* __restrict__ emb, const float* __restrict__ iw1,
    const float* __restrict__ ib1, const float* __restrict__ iw2, const float* __restrict__ ib2,
    u16* __restrict__ table, int V_, const int* __restrict__ src, const int* __restrict__ dst,
    u32* __restrict__ pairs, u32* __restrict__ cursor, int E_, int nbuc) {
  __shared__ u32 smem[1024];  // bucket: lcnt|lbase ; mlp0: e|tt (aliased)
  const int t = threadIdx.x;
  int bid = blockIdx.x;
  if (bid < 384) {  // ---- weight prep
    const int which = bid >> 6;
    const float* w = which == 0 ? w0 : which == 1 ? w1c : which == 2 ? w2c
                    : which == 3 ? w3 : which == 4 ? w4 : w5;
    int tt_ = (bid & 63) * 256 + t;
    int n = tt_ >> 7, k = tt_ & 127;
    wt[which * 16384 + n * 128 + k] = f2bf(w[k * 128 + n]);
    return;
  }
  bid -= 384;
  if (bid < V_) {  // ---- initial MLP on the 500-row embedding table
    float* e = (float*)smem;
    float* tb = e + 128;
    if (t < 128) e[t] = emb[bid * 128 + t];
    __syncthreads();
    if (t < 128) {
      float s = ib1[t];
      for (int k = 0; k < 128; ++k) s += e[k] * iw1[k * 128 + t];
      tb[t] = s > 0.f ? s : 0.f;
    }
    __syncthreads();
    if (t < 128) {
      float s2 = ib2[t];
      for (int k = 0; k < 128; ++k) s2 += tb[k] * iw2[k * 128 + t];
      table[bid * 128 + t] = f2bf(s2);
    }
    return;
  }
  bid -= V_;
  {  // ---- bucket edges by dst>>8, packed (src<<8)|dloc, int4 edge reads
    u32* lcnt = smem;
    u32* lbase = smem + 512;
    for (int b = t; b < NBUC_MAX; b += 256) lcnt[b] = 0;
    __syncthreads();
    const int e0 = bid * EPB;
#pragma unroll
    for (int it = 0; it < EPB / 1024; ++it) {
      int e = e0 + it * 1024 + t * 4;
      if (e + 3 < E_) {
        int4 d4 = *(const int4*)(dst + e);
        atomicAdd(&lcnt[((u32)d4.x) >> 8], 1u);
        atomicAdd(&lcnt[((u32)d4.y) >> 8], 1u);
        atomicAdd(&lcnt[((u32)d4.z) >> 8], 1u);
        atomicAdd(&lcnt[((u32)d4.w) >> 8], 1u);
      } else {
        for (int k = 0; k < 4; ++k)
          if (e + k < E_) atomicAdd(&lcnt[((u32)dst[e + k]) >> 8], 1u);
      }
    }
    __syncthreads();
    for (int b = t; b < nbuc; b += 256) {
      u32 c = lcnt[b];
      lbase[b] = c ? atomicAdd(&cursor[b], c) : 0u;
      lcnt[b] = 0;
    }
    __syncthreads();
#define PUTPAIR(dd, ss)                                            \
  {                                                                \
    u32 b_ = ((u32)(dd)) >> 8;                                     \
    u32 r_ = atomicAdd(&lcnt[b_], 1u);                             \
    u32 p_ = lbase[b_] + r_;                                       \
    if (p_ < BCAP)                                                 \
      pairs[(size_t)b_ * BCAP + p_] = (((u32)(ss)) << 8) | (u32)((dd) & 255); \
  }
#pragma unroll
    for (int it = 0; it < EPB / 1024; ++it) {
      int e = e0 + it * 1024 + t * 4;
      if (e + 3 < E_) {
        int4 d4 = *(const int4*)(dst + e);
        int4 s4 = *(const int4*)(src + e);
        PUTPAIR(d4.x, s4.x)
        PUTPAIR(d4.y, s4.y)
        PUTPAIR(d4.z, s4.z)
        PUTPAIR(d4.w, s4.w)
      } else {
        for (int k = 0; k < 4; ++k)
          if (e + k < E_) PUTPAIR(dst[e + k], src[e + k])
      }
    }
#undef PUTPAIR
  }
}

// ---- per-bucket exact CSR (256 nodes/bucket): LDS count + scan + rank scatter
__global__ __launch_bounds__(256) void csr_build(const u32* __restrict__ pairs,
                                                 const u32* __restrict__ cursor,
                                                 u32* __restrict__ csr, int* __restrict__ RS,
                                                 int* __restrict__ DEG, int nrows) {
  __shared__ u32 cnt[256];
  __shared__ u32 offs[256];
  __shared__ u32 basearr[256];
  const int b = blockIdx.x, t = threadIdx.x;
  u32 count = cursor[b];
  if (count > BCAP) count = BCAP;
  cnt[t] = 0;
  __syncthreads();
  const u32* pb = pairs + (size_t)b * BCAP;
  for (u32 i = t * 4; i < count; i += 1024) {
    if (i + 3 < count) {
      uint4 v4 = *(const uint4*)(pb + i);
      atomicAdd(&cnt[v4.x & 255u], 1u);
      atomicAdd(&cnt[v4.y & 255u], 1u);
      atomicAdd(&cnt[v4.z & 255u], 1u);
      atomicAdd(&cnt[v4.w & 255u], 1u);
    } else {
      for (u32 k = 0; k < 4 && i + k < count; ++k) atomicAdd(&cnt[pb[i + k] & 255u], 1u);
    }
  }
  __syncthreads();
  const u32 my = cnt[t];
  offs[t] = my;
  __syncthreads();
  for (int d = 1; d < 256; d <<= 1) {
    u32 v = (t >= d) ? offs[t - d] : 0u;
    __syncthreads();
    offs[t] += v;
    __syncthreads();
  }
  const u32 excl = offs[t] - my;  // exclusive prefix
  const int node = (b << 8) + t;
  if (node < nrows) {
    RS[node] = b * BCAP + (int)excl;
    DEG[node] = (int)my;
  }
  basearr[t] = excl;
  cnt[t] = 0;
  __syncthreads();
#define SCAT(vv)                                          \
  {                                                       \
    u32 dl_ = (vv) & 255u;                                \
    u32 r_ = atomicAdd(&cnt[dl_], 1u);                    \
    csr[(size_t)b * BCAP + basearr[dl_] + r_] = (vv) >> 8; \
  }
  for (u32 i = t * 4; i < count; i += 1024) {
    if (i + 3 < count) {
      uint4 v4 = *(const uint4*)(pb + i);
      SCAT(v4.x)
      SCAT(v4.y)
      SCAT(v4.z)
      SCAT(v4.w)
    } else {
      for (u32 k = 0; k < 4 && i + k < count; ++k) SCAT(pb[i + k])
    }
  }
#undef SCAT
}

// ---- aggregation (EXACT r13/r15/r16 form — measured optimum 69.0-69.4 us).
// AGG[i] = f(row(i)) + sum_j f(row(j)).  MODE 0: row(i)=TBL[x[i]], f=id.
// MODE 1: row(i)=H[i], f=BN-affine+relu (scsh=[sc|sh] precomputed). Fused per-edge
// BN (r9: separate pass worse). Every inner-loop rewrite regressed (r10/r14/r17/r18)
// — FROZEN PERMANENTLY.
template <int MODE>
__global__ __launch_bounds__(256) void agg_kernel(
    const u16* __restrict__ Hsrc, const int* __restrict__ x, const u32* __restrict__ csr,
    const int* __restrict__ RS, const int* __restrict__ DEG, const float* __restrict__ scsh,
    u16* __restrict__ AGG, int nrows) {
  int node = blockIdx.x * 4 + (threadIdx.x >> 6);
  if (node >= nrows) return;
  const int lane = threadIdx.x & 63;
  const int grp = lane >> 4;  // neighbor sub-slot 0..3
  const int fl = lane & 15;   // 16B feature chunk
  const int deg = DEG[node];
  const u32* cl = csr + RS[node];
  const char* Hb = (const char*)Hsrc;
  const u32 flo = (u32)fl << 4;

  float sc[8], sh[8];
  if (MODE == 1) {
#pragma unroll
    for (int i = 0; i < 8; ++i) {
      sc[i] = scsh[fl * 8 + i];
      sh[i] = scsh[128 + fl * 8 + i];
    }
  }
  float a[8];
#pragma unroll
  for (int i = 0; i < 8; ++i) a[i] = 0.f;

#define ACCUM(vv)                                   \
  {                                                 \
    const u16* p = (const u16*)&(vv);               \
    _Pragma("unroll") for (int i = 0; i < 8; ++i) { \
      float xv = bf2f(p[i]);                        \
      if (MODE == 1) {                              \
        xv = xv * sc[i] + sh[i];                    \
        xv = xv > 0.f ? xv : 0.f;                   \
      }                                             \
      a[i] += xv;                                   \
    }                                               \
  }
#define ROWOFF(idx) ((((u32)(MODE == 0 ? x[(idx)] : (idx))) << 8) + flo)

  if (grp == 0) {
    uint4 v = *(const uint4*)(Hb + ROWOFF(node));
    ACCUM(v);
  }
  int j = grp;
  int cA = (j < deg) ? (int)cl[j] : 0;
  int cB = (j + 4 < deg) ? (int)cl[j + 4] : 0;
  uint4 nv = make_uint4(0u, 0u, 0u, 0u);
  if (j < deg) nv = *(const uint4*)(Hb + ROWOFF(cA));
  while (j < deg) {
    uint4 cv = nv;
    int cn = cB;
    cB = (j + 8 < deg) ? (int)cl[j + 8] : 0;
    if (j + 4 < deg) nv = *(const uint4*)(Hb + ROWOFF(cn));
    ACCUM(cv);
    j += 4;
  }
#undef ROWOFF
#undef ACCUM

#pragma unroll
  for (int i = 0; i < 8; ++i) {
    a[i] += __shfl_xor(a[i], 16);
    a[i] += __shfl_xor(a[i], 32);
  }
  if (grp == 0) {
    u32 o[4];
#pragma unroll
    for (int i = 0; i < 4; ++i) o[i] = f2bf_pk(a[2 * i], a[2 * i + 1]);
    *(uint4*)(AGG + (size_t)node * 128 + fl * 8) = *(uint4*)o;
  }
}

// ---- fused 2-layer MLP (bf16 MFMA), 128x128 tile, 4 waves, T in-place, coalesced
// C-store via Xs (r13), HW cvt epilogues (r14), PART stats (r12). FROZEN.
__global__ __launch_bounds__(256) void mlp_kernel(
    const u16* __restrict__ X, const u16* __restrict__ W1t, const float* __restrict__ b1,
    const u16* __restrict__ W2t, const float* __restrict__ b2, u16* __restrict__ Y,
    float* __restrict__ part, int nrows) {
  __shared__ u16 Xs[128 * 136];
  const int t = threadIdx.x;
  const int row0 = blockIdx.x * 128;
  {
    const int seg = t & 15;
    const int rb = t >> 4;
#pragma unroll
    for (int p = 0; p < 8; ++p) {
      const int r = rb + p * 16;
      const int gr = row0 + r;
      uint4 v = make_uint4(0u, 0u, 0u, 0u);
      if (gr < nrows) v = *(const uint4*)(X + (size_t)gr * 128 + seg * 8);
      *(uint4*)(Xs + r * 136 + seg * 8) = v;
    }
  }
  __syncthreads();
  const int lane = t & 63;
  const int wave = t >> 6;
  const int n0 = wave * 32;
  const int nl = lane & 15;
  const int quad = lane >> 4;

  bf16x8 bw[2][4];
#pragma unroll
  for (int nt = 0; nt < 2; ++nt)
#pragma unroll
    for (int kk = 0; kk < 4; ++kk)
      bw[nt][kk] = *(const bf16x8*)(W1t + (size_t)(n0 + nt * 16 + nl) * 128 + kk * 32 + quad * 8);

  f32x4 acc[8][2];
#pragma unroll
  for (int mt = 0; mt < 8; ++mt) {
    acc[mt][0] = (f32x4)0.0f;
    acc[mt][1] = (f32x4)0.0f;
  }
#pragma unroll
  for (int kk = 0; kk < 4; ++kk) {
#pragma unroll
    for (int mt = 0; mt < 8; ++mt) {
      bf16x8 a = *(const bf16x8*)(Xs + (mt * 16 + nl) * 136 + kk * 32 + quad * 8);
      acc[mt][0] = MFMA_BF16(a, bw[0][kk], acc[mt][0]);
      acc[mt][1] = MFMA_BF16(a, bw[1][kk], acc[mt][1]);
    }
  }
  __syncthreads();  // all GEMM1 A-reads complete before overwriting Xs with T
#pragma unroll
  for (int nt = 0; nt < 2; ++nt) {
    const int n = n0 + nt * 16 + nl;
    const float bias = b1[n];
#pragma unroll
    for (int mt = 0; mt < 8; ++mt)
#pragma unroll
      for (int r = 0; r < 4; ++r) {
        float v = acc[mt][nt][r] + bias;
        v = v > 0.f ? v : 0.f;
        Xs[(mt * 16 + quad * 4 + r) * 136 + n] = f2bf(v);
      }
  }
  __syncthreads();
  // GEMM2
#pragma unroll
  for (int nt = 0; nt < 2; ++nt)
#pragma unroll
    for (int kk = 0; kk < 4; ++kk)
      bw[nt][kk] = *(const bf16x8*)(W2t + (size_t)(n0 + nt * 16 + nl) * 128 + kk * 32 + quad * 8);
#pragma unroll
  for (int mt = 0; mt < 8; ++mt) {
    acc[mt][0] = (f32x4)0.0f;
    acc[mt][1] = (f32x4)0.0f;
  }
#pragma unroll
  for (int kk = 0; kk < 4; ++kk) {
#pragma unroll
    for (int mt = 0; mt < 8; ++mt) {
      bf16x8 a = *(const bf16x8*)(Xs + (mt * 16 + nl) * 136 + kk * 32 + quad * 8);
      acc[mt][0] = MFMA_BF16(a, bw[0][kk], acc[mt][0]);
      acc[mt][1] = MFMA_BF16(a, bw[1][kk], acc[mt][1]);
    }
  }
  __syncthreads();  // all GEMM2 A-reads complete before overwriting Xs with C
  float ssum[2] = {0.f, 0.f}, ssq[2] = {0.f, 0.f};
#pragma unroll
  for (int nt = 0; nt < 2; ++nt) {
    const int n = n0 + nt * 16 + nl;
    const float bias = b2[n];
#pragma unroll
    for (int mt = 0; mt < 8; ++mt)
#pragma unroll
      for (int r = 0; r < 4; ++r) {
        const int row = row0 + mt * 16 + quad * 4 + r;
        float v = acc[mt][nt][r] + bias;
        if (row < nrows) {
          ssum[nt] += v;
          ssq[nt] += v * v;
        }
        Xs[(mt * 16 + quad * 4 + r) * 136 + n] = f2bf(v);
      }
  }
#pragma unroll
  for (int nt = 0; nt < 2; ++nt) {
    float s = ssum[nt], q = ssq[nt];
    s += __shfl_xor(s, 16);
    q += __shfl_xor(q, 16);
    s += __shfl_xor(s, 32);
    q += __shfl_xor(q, 32);
    if (quad == 0) {
      const int n = n0 + nt * 16 + nl;
      part[(size_t)blockIdx.x * 256 + n] = s;
      part[(size_t)blockIdx.x * 256 + 128 + n] = q;
    }
  }
  __syncthreads();
  {
    const int seg = t & 15;
    const int rb = t >> 4;
#pragma unroll
    for (int p = 0; p < 8; ++p) {
      const int r = rb + p * 16;
      const int gr = row0 + r;
      if (gr < nrows)
        *(uint4*)(Y + (size_t)gr * 128 + seg * 8) = *(const uint4*)(Xs + r * 136 + seg * 8);
    }
  }
}

// ---- parallel column-reduce of PART + scale/shift compute (r12-proven, ~free)
__global__ __launch_bounds__(256) void bn_reduce_finalize(
    const float* __restrict__ part, int nblk, const float* __restrict__ g,
    const float* __restrict__ be, float invN, float* __restrict__ scsh) {
  __shared__ float red[2][128];
  const int c = blockIdx.x;  // 0..127
  const int t = threadIdx.x;
  const int half = t >> 7;
  const int tt = t & 127;
  const int col = c + half * 128;
  float s = 0.f;
  for (int b = tt; b < nblk; b += 128) s += part[(size_t)b * 256 + col];
  red[half][tt] = s;
  __syncthreads();
  for (int d = 64; d > 0; d >>= 1) {
    if (tt < d) red[half][tt] += red[half][tt + d];
    __syncthreads();
  }
  if (t == 0) {
    float mu = red[0][0] * invN;
    float var = red[1][0] * invN - mu * mu;
    float rstd = rsqrtf(var + 1e-5f);
    float sc = rstd * g[c];
    scsh[c] = sc;
    scsh[128 + c] = be[c] - mu * sc;
  }
}

// ---- pooling (fused layer-3 BN+relu via precomputed scsh) + final head, one block/graph
__global__ __launch_bounds__(256) void pool_final(
    const u16* __restrict__ Hh, const int* __restrict__ batch, const float* __restrict__ scsh,
    const float* __restrict__ f1w, const float* __restrict__ f1b, const float* __restrict__ f2w,
    const float* __restrict__ f2b, float* __restrict__ out, int nrows) {
  __shared__ float red[16][128];
  __shared__ float pr[128];
  __shared__ float tt[128];
  const int gid = blockIdx.x, t = threadIdx.x;
  int l = 0, r = nrows;
  while (l < r) {
    int m = (l + r) >> 1;
    if (batch[m] < gid) l = m + 1; else r = m;
  }
  const int s0 = l;
  r = nrows;
  while (l < r) {
    int m = (l + r) >> 1;
    if (batch[m] < gid + 1) l = m + 1; else r = m;
  }
  const int s1 = l;
  const int fl = t & 15;
  const int grp = t >> 4;
  float sc[8], sh[8];
#pragma unroll
  for (int i = 0; i < 8; ++i) {
    sc[i] = scsh[fl * 8 + i];
    sh[i] = scsh[128 + fl * 8 + i];
  }
  float a[8];
#pragma unroll
  for (int i = 0; i < 8; ++i) a[i] = 0.f;
  for (int i = s0 + grp; i < s1; i += 16) {
    uint4 v = *(const uint4*)(Hh + (size_t)i * 128 + fl * 8);
    const u16* pp = (const u16*)&v;
#pragma unroll
    for (int k = 0; k < 8; ++k) {
      float xv = bf2f(pp[k]) * sc[k] + sh[k];
      a[k] += xv > 0.f ? xv : 0.f;
    }
  }
#pragma unroll
  for (int k = 0; k < 8; ++k) red[grp][fl * 8 + k] = a[k];
  __syncthreads();
  if (t < 128) {
    float s = 0.f;
#pragma unroll
    for (int gg2 = 0; gg2 < 16; ++gg2) s += red[gg2][t];
    pr[t] = s;
  }
  __syncthreads();
  if (t < 128) {
    float s = f1b[t];
    for (int k = 0; k < 128; ++k) s += pr[k] * f1w[k * 128 + t];
    tt[t] = s > 0.f ? s : 0.f;
  }
  __syncthreads();
  if (t < 10) {
    float s2 = f2b[t];
    for (int k = 0; k < 128; ++k) s2 += tt[k] * f2w[k * 10 + t];
    out[gid * 10 + t] = s2;
  }
}

// ws layout (bytes):
//   H     @ 0          : 25,600,000
//   AGG   @ 25,600,000 : 25,600,000
//   PAIRS @ 51,200,000 : 9,437,184
//   CSR   @ 60,637,184 : 9,437,184
//   RS    @ 70,074,368 : 400,000
//   DEG   @ 70,474,368 : 400,000
//   CUR   @ 70,874,368 : 2,048       (zeroed)
//   SCSH  @ 70,876,416 : 3,072       (3 layers x [sc|sh] = 256 f32)
//   WT    @ 70,879,488 : 196,608
//   TBL   @ 71,076,096 : 128,000
//   PART  @ 71,204,096 : 800,768
extern "C" void kernel_launch(void* const* d_in, const int* in_sizes, int n_in, void* d_out,
                              int out_size, void* d_ws, size_t ws_size, hipStream_t stream) {
  const int* x = (const int*)d_in[0];
  const int* ei = (const int*)d_in[1];
  const int* batch = (const int*)d_in[2];
  const float* emb = (const float*)d_in[3];
  const float* iw1 = (const float*)d_in[4];
  const float* ib1 = (const float*)d_in[5];
  const float* iw2 = (const float*)d_in[6];
  const float* ib2 = (const float*)d_in[7];
  const float* f1w = (const float*)d_in[8];
  const float* f1b = (const float*)d_in[9];
  const float* f2w = (const float*)d_in[10];
  const float* f2b = (const float*)d_in[11];
  const float* cw1[3] = {(const float*)d_in[12], (const float*)d_in[18], (const float*)d_in[24]};
  const float* cb1[3] = {(const float*)d_in[13], (const float*)d_in[19], (const float*)d_in[25]};
  const float* cw2[3] = {(const float*)d_in[14], (const float*)d_in[20], (const float*)d_in[26]};
  const float* cb2[3] = {(const float*)d_in[15], (const float*)d_in[21], (const float*)d_in[27]};
  const float* gg[3] = {(const float*)d_in[16], (const float*)d_in[22], (const float*)d_in[28]};
  const float* bb[3] = {(const float*)d_in[17], (const float*)d_in[23], (const float*)d_in[29]};

  const int N_ = in_sizes[0];
  const int E_ = in_sizes[1] / 2;
  const int V_ = in_sizes[3] / 128;
  const int G_ = out_size / 10;
  const int NBUC = (N_ + 255) >> 8;
  const int NBUCKBLK = (E_ + EPB - 1) / EPB;
  const float invN = 1.0f / (float)N_;

  char* ws = (char*)d_ws;
  u16* H = (u16*)(ws + 0);
  u16* AGG = (u16*)(ws + 25600000);
  u32* PAIRS = (u32*)(ws + 51200000);
  u32* CSR = (u32*)(ws + 60637184);
  int* RS = (int*)(ws + 70074368);
  int* DEG = (int*)(ws + 70474368);
  u32* CUR = (u32*)(ws + 70874368);
  float* SCSH = (float*)(ws + 70876416);
  u16* WT = (u16*)(ws + 70879488);
  u16* TBL = (u16*)(ws + 71076096);
  float* PART = (float*)(ws + 71204096);

  hipMemsetAsync(ws + 70874368, 0, 2048, stream);  // CUR only

  setup_all<<<384 + V_ + NBUCKBLK, 256, 0, stream>>>(
      cw1[0], cw2[0], cw1[1], cw2[1], cw1[2], cw2[2], WT, emb, iw1, ib1, iw2, ib2, TBL, V_,
      ei, ei + E_, PAIRS, CUR, E_, NBUC);
  csr_build<<<NBUC, 256, 0, stream>>>(PAIRS, CUR, CSR, RS, DEG, N_);

  const int ablk = (N_ + 3) / 4;
  const int mblk = (N_ + 127) / 128;
  for (int l = 0; l < 3; ++l) {
    const u16* W1 = WT + (size_t)l * 32768;
    const u16* W2 = WT + (size_t)l * 32768 + 16384;
    if (l == 0)
      agg_kernel<0><<<ablk, 256, 0, stream>>>(TBL, x, CSR, RS, DEG, nullptr, AGG, N_);
    else
      agg_kernel<1><<<ablk, 256, 0, stream>>>(H, nullptr, CSR, RS, DEG, SCSH + (l - 1) * 256,
                                              AGG, N_);
    mlp_kernel<<<mblk, 256, 0, stream>>>(AGG, W1, cb1[l], W2, cb2[l], H, PART, N_);
    bn_reduce_finalize<<<128, 256, 0, stream>>>(PART, mblk, gg[l], bb[l], invN,
                                                SCSH + l * 256);
  }
  pool_final<<<G_, 256, 0, stream>>>(H, batch, SCSH + 2 * 256, f1w, f1b, f2w, f2b,
                                     (float*)d_out, N_);
}